// Round 2
// baseline (2279.663 us; speedup 1.0000x reference)
//
#include <hip/hip_runtime.h>
#include <math.h>

#define T_SEQ 2048
#define D_MODEL 1024
#define NH 16
#define HD 64
#define RMS_EPS 1.1920928955078125e-07f

// ---------------------------------------------------------------------------
// C[M,N] = A[M,K] @ B[N,K]^T   (A row-major MxK, B row-major NxK)
// 64x64 tile, 256 threads, each thread computes 4x4. K-chunk 16.
// ---------------------------------------------------------------------------
__global__ __launch_bounds__(256) void gemm_nt(const float* __restrict__ A,
                                               const float* __restrict__ B,
                                               float* __restrict__ C,
                                               int M, int N, int K) {
    __shared__ float As[64][17];
    __shared__ float Bs[64][17];
    const int tid = threadIdx.x;
    const int row0 = blockIdx.y * 64;
    const int col0 = blockIdx.x * 64;
    const int lr = tid >> 2;          // 0..63
    const int lc = (tid & 3) * 4;     // 0,4,8,12
    const int ty = tid >> 4;          // 0..15
    const int tx = tid & 15;          // 0..15

    float acc[4][4] = {};

    for (int k0 = 0; k0 < K; k0 += 16) {
        float4 av = *(const float4*)&A[(size_t)(row0 + lr) * K + k0 + lc];
        float4 bv = *(const float4*)&B[(size_t)(col0 + lr) * K + k0 + lc];
        As[lr][lc + 0] = av.x; As[lr][lc + 1] = av.y;
        As[lr][lc + 2] = av.z; As[lr][lc + 3] = av.w;
        Bs[lr][lc + 0] = bv.x; Bs[lr][lc + 1] = bv.y;
        Bs[lr][lc + 2] = bv.z; Bs[lr][lc + 3] = bv.w;
        __syncthreads();
#pragma unroll
        for (int kk = 0; kk < 16; ++kk) {
            float a[4], b[4];
#pragma unroll
            for (int i = 0; i < 4; ++i) a[i] = As[ty * 4 + i][kk];
#pragma unroll
            for (int j = 0; j < 4; ++j) b[j] = Bs[tx * 4 + j][kk];
#pragma unroll
            for (int i = 0; i < 4; ++i)
#pragma unroll
                for (int j = 0; j < 4; ++j) acc[i][j] += a[i] * b[j];
        }
        __syncthreads();
    }
#pragma unroll
    for (int i = 0; i < 4; ++i)
#pragma unroll
        for (int j = 0; j < 4; ++j)
            C[(size_t)(row0 + ty * 4 + i) * N + col0 + tx * 4 + j] = acc[i][j];
}

// ---------------------------------------------------------------------------
// Fused: v = (1-lam)*v + lam*vi ; q,k = rmsnorm per (t,h) ; q,k = rope
// One 64-lane wave per (t, h). lane = d within head.
// ---------------------------------------------------------------------------
__global__ __launch_bounds__(64) void norm_rope(float* __restrict__ q,
                                                float* __restrict__ k,
                                                float* __restrict__ v,
                                                const float* __restrict__ vi,
                                                const float* __restrict__ lamb) {
    const int t = blockIdx.x;
    const int h = blockIdx.y;
    const int lane = threadIdx.x;
    const size_t idx = (size_t)t * D_MODEL + h * HD + lane;

    const float lam = lamb[0];
    float qv = q[idx];
    float kv = k[idx];
    float vv = (1.0f - lam) * v[idx] + lam * vi[idx];
    v[idx] = vv;

    // RMS over 64 lanes
    float sq = qv * qv;
    float sk = kv * kv;
#pragma unroll
    for (int m = 1; m <= 32; m <<= 1) {
        sq += __shfl_xor(sq, m, 64);
        sk += __shfl_xor(sk, m, 64);
    }
    const float rq = rsqrtf(sq * (1.0f / 64.0f) + RMS_EPS);
    const float rk = rsqrtf(sk * (1.0f / 64.0f) + RMS_EPS);
    float qn = qv * rq;
    float kn = kv * rk;

    // RoPE: pair (i, i+32); y1 = x1*c + x2*s ; y2 = -x1*s + x2*c
    const int i = lane & 31;
    const float inv = powf(1.0f / 10000.0f, (float)(2 * i) / 64.0f);
    const float ang = (float)t * inv;
    float c, s;
    sincosf(ang, &s, &c);
    float qp = __shfl_xor(qn, 32, 64);
    float kp = __shfl_xor(kn, 32, 64);
    float qo, ko;
    if (lane < 32) {
        qo = qn * c + qp * s;
        ko = kn * c + kp * s;
    } else {
        qo = qn * c - qp * s;
        ko = kn * c - kp * s;
    }
    q[idx] = qo;
    k[idx] = ko;
}

// ---------------------------------------------------------------------------
// Flash attention, f32. Block = 256 threads handles (head, 64-query tile).
// Thread layout: wave w handles rows w*16..w*16+15; within a row-group of 4
// lanes, lane kg handles keys {kg, kg+4, ...} (16 of 64) and dims kg*16..+15.
// ---------------------------------------------------------------------------
__global__ __launch_bounds__(256) void attn(const float* __restrict__ q,
                                            const float* __restrict__ k,
                                            const float* __restrict__ v,
                                            const float* __restrict__ sink,
                                            float* __restrict__ y) {
    const int qt = blockIdx.x;   // query tile, 0..31
    const int h  = blockIdx.y;   // head

    __shared__ float Qs[64][HD + 1];
    __shared__ float Ks[64][HD + 1];
    __shared__ float Vs[64][HD + 1];
    __shared__ float Ps[64][64 + 1];

    const int tid  = threadIdx.x;
    const int lr   = tid >> 2;            // 0..63 (row for loading)
    const int lc0  = (tid & 3) * 16;      // load col start
    const int wave = tid >> 6;
    const int lane = tid & 63;
    const int r    = wave * 16 + (lane >> 2);  // my query row in tile
    const int kg   = lane & 3;                 // key/dim group

    // load Q tile
#pragma unroll
    for (int u = 0; u < 4; ++u) {
        float4 t4 = *(const float4*)&q[(size_t)(qt * 64 + lr) * D_MODEL + h * HD + lc0 + u * 4];
        Qs[lr][lc0 + u * 4 + 0] = t4.x; Qs[lr][lc0 + u * 4 + 1] = t4.y;
        Qs[lr][lc0 + u * 4 + 2] = t4.z; Qs[lr][lc0 + u * 4 + 3] = t4.w;
    }
    __syncthreads();

    float m = -INFINITY;
    float l = 0.0f;
    float acc[16];
#pragma unroll
    for (int i = 0; i < 16; ++i) acc[i] = 0.0f;

    const int gq = qt * 64 + r;

    for (int kt = 0; kt <= qt; ++kt) {
        // stage K and V tiles
#pragma unroll
        for (int u = 0; u < 4; ++u) {
            float4 kt4 = *(const float4*)&k[(size_t)(kt * 64 + lr) * D_MODEL + h * HD + lc0 + u * 4];
            float4 vt4 = *(const float4*)&v[(size_t)(kt * 64 + lr) * D_MODEL + h * HD + lc0 + u * 4];
            Ks[lr][lc0 + u * 4 + 0] = kt4.x; Ks[lr][lc0 + u * 4 + 1] = kt4.y;
            Ks[lr][lc0 + u * 4 + 2] = kt4.z; Ks[lr][lc0 + u * 4 + 3] = kt4.w;
            Vs[lr][lc0 + u * 4 + 0] = vt4.x; Vs[lr][lc0 + u * 4 + 1] = vt4.y;
            Vs[lr][lc0 + u * 4 + 2] = vt4.z; Vs[lr][lc0 + u * 4 + 3] = vt4.w;
        }
        __syncthreads();

        // scores for my 16 keys
        float sc[16];
        float mt = -INFINITY;
#pragma unroll
        for (int j = 0; j < 16; ++j) {
            const int kk = kg + j * 4;
            float d = 0.0f;
#pragma unroll
            for (int dd = 0; dd < HD; ++dd) d += Qs[r][dd] * Ks[kk][dd];
            d *= 0.125f;
            if (kt * 64 + kk > gq) d = -INFINITY;
            sc[j] = d;
            mt = fmaxf(mt, d);
        }
        // reduce max over the 4 lanes of this row
        mt = fmaxf(mt, __shfl_xor(mt, 1, 64));
        mt = fmaxf(mt, __shfl_xor(mt, 2, 64));

        const float mnew = fmaxf(m, mt);
        const float corr = expf(m - mnew);   // exp(-inf)=0 on first tile
        float psum = 0.0f;
#pragma unroll
        for (int j = 0; j < 16; ++j) {
            const float p = expf(sc[j] - mnew);
            Ps[r][kg + j * 4] = p;
            psum += p;
        }
        psum += __shfl_xor(psum, 1, 64);
        psum += __shfl_xor(psum, 2, 64);
        l = l * corr + psum;
        m = mnew;
#pragma unroll
        for (int i = 0; i < 16; ++i) acc[i] *= corr;

        __syncthreads();  // Ps visible (same wave anyway), keep uniform

        // PV: dims kg*16 .. +15
#pragma unroll
        for (int kk = 0; kk < 64; ++kk) {
            const float p = Ps[r][kk];
#pragma unroll
            for (int i = 0; i < 16; ++i) acc[i] += p * Vs[kk][kg * 16 + i];
        }
        __syncthreads();  // before next tile overwrites K/V
    }

    const float lse = m + logf(l);
    const float scale = 1.0f / (1.0f + expf(-(lse - sink[h])));
    const float f = scale / l;
#pragma unroll
    for (int i = 0; i < 16; ++i)
        y[(size_t)gq * D_MODEL + h * HD + kg * 16 + i] = acc[i] * f;
}

// ---------------------------------------------------------------------------
extern "C" void kernel_launch(void* const* d_in, const int* in_sizes, int n_in,
                              void* d_out, int out_size, void* d_ws, size_t ws_size,
                              hipStream_t stream) {
    const float* x    = (const float*)d_in[0];
    const float* vi   = (const float*)d_in[1];
    const float* Wq   = (const float*)d_in[2];
    const float* Wk   = (const float*)d_in[3];
    const float* Wv   = (const float*)d_in[4];
    const float* Wo   = (const float*)d_in[5];
    const float* lamb = (const float*)d_in[6];
    const float* sink = (const float*)d_in[7];
    float* out = (float*)d_out;

    const size_t TD = (size_t)T_SEQ * D_MODEL;
    float* q = (float*)d_ws;
    float* k = q + TD;
    float* v = k + TD;
    float* y = v + TD;

    dim3 gg(D_MODEL / 64, T_SEQ / 64);
    gemm_nt<<<gg, 256, 0, stream>>>(x, Wq, q, T_SEQ, D_MODEL, D_MODEL);
    gemm_nt<<<gg, 256, 0, stream>>>(x, Wk, k, T_SEQ, D_MODEL, D_MODEL);
    gemm_nt<<<gg, 256, 0, stream>>>(x, Wv, v, T_SEQ, D_MODEL, D_MODEL);

    norm_rope<<<dim3(T_SEQ, NH), 64, 0, stream>>>(q, k, v, vi, lamb);

    attn<<<dim3(T_SEQ / 64, NH), 256, 0, stream>>>(q, k, v, sink, y);

    gemm_nt<<<gg, 256, 0, stream>>>(y, Wo, out, T_SEQ, D_MODEL, D_MODEL);
}

// Round 3
// 566.463 us; speedup vs baseline: 4.0244x; 4.0244x over previous
//
#include <hip/hip_runtime.h>
#include <hip/hip_bf16.h>
#include <math.h>

#define T_SEQ 2048
#define D_MODEL 1024
#define NH 16
#define HD 64
#define RMS_EPS 1.1920928955078125e-07f

typedef __attribute__((ext_vector_type(8))) short short8;
typedef __attribute__((ext_vector_type(4))) float f32x4;

static __device__ __forceinline__ unsigned short f2bf(float f) {
    union { float f; unsigned u; } v; v.f = f;
    unsigned r = v.u + 0x7fff + ((v.u >> 16) & 1);   // RNE
    return (unsigned short)(r >> 16);
}

// ---------------------------------------------------------------------------
// C[M,N] = A[M,K] @ B[N,K]^T  (f32, unchanged from baseline)
// ---------------------------------------------------------------------------
__global__ __launch_bounds__(256) void gemm_nt(const float* __restrict__ A,
                                               const float* __restrict__ B,
                                               float* __restrict__ C,
                                               int M, int N, int K) {
    __shared__ float As[64][17];
    __shared__ float Bs[64][17];
    const int tid = threadIdx.x;
    const int row0 = blockIdx.y * 64;
    const int col0 = blockIdx.x * 64;
    const int lr = tid >> 2;
    const int lc = (tid & 3) * 4;
    const int ty = tid >> 4;
    const int tx = tid & 15;

    float acc[4][4] = {};

    for (int k0 = 0; k0 < K; k0 += 16) {
        float4 av = *(const float4*)&A[(size_t)(row0 + lr) * K + k0 + lc];
        float4 bv = *(const float4*)&B[(size_t)(col0 + lr) * K + k0 + lc];
        As[lr][lc + 0] = av.x; As[lr][lc + 1] = av.y;
        As[lr][lc + 2] = av.z; As[lr][lc + 3] = av.w;
        Bs[lr][lc + 0] = bv.x; Bs[lr][lc + 1] = bv.y;
        Bs[lr][lc + 2] = bv.z; Bs[lr][lc + 3] = bv.w;
        __syncthreads();
#pragma unroll
        for (int kk = 0; kk < 16; ++kk) {
            float a[4], b[4];
#pragma unroll
            for (int i = 0; i < 4; ++i) a[i] = As[ty * 4 + i][kk];
#pragma unroll
            for (int j = 0; j < 4; ++j) b[j] = Bs[tx * 4 + j][kk];
#pragma unroll
            for (int i = 0; i < 4; ++i)
#pragma unroll
                for (int j = 0; j < 4; ++j) acc[i][j] += a[i] * b[j];
        }
        __syncthreads();
    }
#pragma unroll
    for (int i = 0; i < 4; ++i)
#pragma unroll
        for (int j = 0; j < 4; ++j)
            C[(size_t)(row0 + ty * 4 + i) * N + col0 + tx * 4 + j] = acc[i][j];
}

// ---------------------------------------------------------------------------
// Fused: v = (1-lam)*v + lam*vi ; q,k = rmsnorm ; q,k = rope ; emit bf16
// One 64-lane wave per (t, h).
// ---------------------------------------------------------------------------
__global__ __launch_bounds__(64) void norm_rope(const float* __restrict__ qf,
                                                const float* __restrict__ kf,
                                                const float* __restrict__ vf,
                                                const float* __restrict__ vi,
                                                const float* __restrict__ lamb,
                                                unsigned short* __restrict__ qb,
                                                unsigned short* __restrict__ kb,
                                                unsigned short* __restrict__ vb) {
    const int t = blockIdx.x;
    const int h = blockIdx.y;
    const int lane = threadIdx.x;
    const size_t idx = (size_t)t * D_MODEL + h * HD + lane;

    const float lam = lamb[0];
    float qv = qf[idx];
    float kv = kf[idx];
    float vv = (1.0f - lam) * vf[idx] + lam * vi[idx];
    vb[idx] = f2bf(vv);

    float sq = qv * qv;
    float sk = kv * kv;
#pragma unroll
    for (int m = 1; m <= 32; m <<= 1) {
        sq += __shfl_xor(sq, m, 64);
        sk += __shfl_xor(sk, m, 64);
    }
    const float rq = rsqrtf(sq * (1.0f / 64.0f) + RMS_EPS);
    const float rk = rsqrtf(sk * (1.0f / 64.0f) + RMS_EPS);
    float qn = qv * rq;
    float kn = kv * rk;

    const int i = lane & 31;
    const float inv = powf(1.0f / 10000.0f, (float)(2 * i) / 64.0f);
    const float ang = (float)t * inv;
    float c, s;
    sincosf(ang, &s, &c);
    float qp = __shfl_xor(qn, 32, 64);
    float kp = __shfl_xor(kn, 32, 64);
    float qo, ko;
    if (lane < 32) {
        qo = qn * c + qp * s;
        ko = kn * c + kp * s;
    } else {
        qo = qn * c - qp * s;
        ko = kn * c - kp * s;
    }
    qb[idx] = f2bf(qo);
    kb[idx] = f2bf(ko);
}

// ---------------------------------------------------------------------------
// Flash attention, bf16 MFMA (16x16x32). Block = 256 thr = 4 waves,
// handles (head h, 64-query tile qt). Wave w owns q-rows w*16..w*16+15.
// Q,K frags straight from global (L2-resident); V staged transposed in LDS;
// P round-trips through per-wave LDS (C-layout -> A-layout).
// MFMA layouts (guide-verified): A[row=l&15][k=8*(l>>4)+j],
// B[k=8*(l>>4)+j][col=l&15], C/D[row=(l>>4)*4+r][col=l&15].
// ---------------------------------------------------------------------------
__global__ __launch_bounds__(256) void attn_mfma(const unsigned short* __restrict__ qb,
                                                 const unsigned short* __restrict__ kb,
                                                 const unsigned short* __restrict__ vb,
                                                 const float* __restrict__ sink,
                                                 float* __restrict__ y) {
    const int qt = blockIdx.x;
    const int h  = blockIdx.y;

    __shared__ unsigned short Vt[64][72];      // V transposed: [d][key], pad 72
    __shared__ unsigned short Pl[4][16][72];   // per-wave P: [q-row][key], pad 72

    const int tid  = threadIdx.x;
    const int w    = tid >> 6;
    const int lane = tid & 63;
    const int l16  = lane & 15;
    const int g4   = lane >> 4;

    // Q fragments (persist across kt loop)
    const size_t qoff = (size_t)(qt * 64 + w * 16 + l16) * D_MODEL + h * HD;
    short8 aq0 = *(const short8*)&qb[qoff + 8 * g4];
    short8 aq1 = *(const short8*)&qb[qoff + 32 + 8 * g4];

    float m[4], lsum[4];
    f32x4 acc[4];
#pragma unroll
    for (int r = 0; r < 4; ++r) {
        m[r] = -INFINITY; lsum[r] = 0.0f;
        acc[r] = (f32x4){0.0f, 0.0f, 0.0f, 0.0f};
    }

    for (int kt = 0; kt <= qt; ++kt) {
        // ---- stage V tile transposed: wave w stages d-cols w*16..+15 ----
        {
            const size_t voff = (size_t)(kt * 64 + lane) * D_MODEL + h * HD + w * 16;
            short8 v0 = *(const short8*)&vb[voff];
            short8 v1 = *(const short8*)&vb[voff + 8];
#pragma unroll
            for (int j = 0; j < 8; ++j) {
                Vt[w * 16 + j][lane]     = (unsigned short)v0[j];
                Vt[w * 16 + 8 + j][lane] = (unsigned short)v1[j];
            }
        }
        __syncthreads();

        // ---- S = Q K^T for 4 key sub-tiles of 16 ----
        float p[4][4];          // [sub][reg]
        float mt[4] = {-INFINITY, -INFINITY, -INFINITY, -INFINITY};
#pragma unroll
        for (int s = 0; s < 4; ++s) {
            const size_t koff = (size_t)(kt * 64 + s * 16 + l16) * D_MODEL + h * HD;
            short8 bk0 = *(const short8*)&kb[koff + 8 * g4];
            short8 bk1 = *(const short8*)&kb[koff + 32 + 8 * g4];
            f32x4 sf = (f32x4){0.0f, 0.0f, 0.0f, 0.0f};
            sf = __builtin_amdgcn_mfma_f32_16x16x32_bf16(aq0, bk0, sf, 0, 0, 0);
            sf = __builtin_amdgcn_mfma_f32_16x16x32_bf16(aq1, bk1, sf, 0, 0, 0);
            const int kglob = kt * 64 + s * 16 + l16;
#pragma unroll
            for (int r = 0; r < 4; ++r) {
                float sc = sf[r] * 0.125f;
                const int qglob = qt * 64 + w * 16 + g4 * 4 + r;
                if (kglob > qglob) sc = -INFINITY;
                p[s][r] = sc;
                mt[r] = fmaxf(mt[r], sc);
            }
        }
        // row max over the 16 lanes of each row group
#pragma unroll
        for (int mk = 1; mk <= 8; mk <<= 1)
#pragma unroll
            for (int r = 0; r < 4; ++r)
                mt[r] = fmaxf(mt[r], __shfl_xor(mt[r], mk, 64));

        float corr[4], ps[4];
#pragma unroll
        for (int r = 0; r < 4; ++r) {
            const float mnew = fmaxf(m[r], mt[r]);
            corr[r] = expf(m[r] - mnew);
            m[r] = mnew;
            ps[r] = 0.0f;
        }
#pragma unroll
        for (int s = 0; s < 4; ++s)
#pragma unroll
            for (int r = 0; r < 4; ++r) {
                const float pv = expf(p[s][r] - m[r]);
                ps[r] += pv;
                Pl[w][g4 * 4 + r][s * 16 + l16] = f2bf(pv);
            }
#pragma unroll
        for (int mk = 1; mk <= 8; mk <<= 1)
#pragma unroll
            for (int r = 0; r < 4; ++r)
                ps[r] += __shfl_xor(ps[r], mk, 64);
#pragma unroll
        for (int r = 0; r < 4; ++r) {
            lsum[r] = lsum[r] * corr[r] + ps[r];
#pragma unroll
            for (int d = 0; d < 4; ++d) acc[d][r] *= corr[r];
        }

        // ---- PV: read P back in A-layout (wave-local, no barrier needed) ----
        short8 pa0 = *(const short8*)&Pl[w][l16][8 * g4];
        short8 pa1 = *(const short8*)&Pl[w][l16][32 + 8 * g4];
#pragma unroll
        for (int d = 0; d < 4; ++d) {
            short8 bv0 = *(const short8*)&Vt[d * 16 + l16][8 * g4];
            short8 bv1 = *(const short8*)&Vt[d * 16 + l16][32 + 8 * g4];
            acc[d] = __builtin_amdgcn_mfma_f32_16x16x32_bf16(pa0, bv0, acc[d], 0, 0, 0);
            acc[d] = __builtin_amdgcn_mfma_f32_16x16x32_bf16(pa1, bv1, acc[d], 0, 0, 0);
        }
        __syncthreads();   // before next iteration overwrites Vt
    }

    const float sw = sink[h];
#pragma unroll
    for (int r = 0; r < 4; ++r) {
        const float lse = m[r] + logf(lsum[r]);
        const float scale = 1.0f / (1.0f + expf(-(lse - sw)));
        const float f = scale / lsum[r];
        const size_t yoff = (size_t)(qt * 64 + w * 16 + g4 * 4 + r) * D_MODEL + h * HD + l16;
#pragma unroll
        for (int d = 0; d < 4; ++d)
            y[yoff + d * 16] = acc[d][r] * f;
    }
}

// ---------------------------------------------------------------------------
extern "C" void kernel_launch(void* const* d_in, const int* in_sizes, int n_in,
                              void* d_out, int out_size, void* d_ws, size_t ws_size,
                              hipStream_t stream) {
    const float* x    = (const float*)d_in[0];
    const float* vi   = (const float*)d_in[1];
    const float* Wq   = (const float*)d_in[2];
    const float* Wk   = (const float*)d_in[3];
    const float* Wv   = (const float*)d_in[4];
    const float* Wo   = (const float*)d_in[5];
    const float* lamb = (const float*)d_in[6];
    const float* sink = (const float*)d_in[7];
    float* out = (float*)d_out;

    const size_t TD = (size_t)T_SEQ * D_MODEL;
    float* qf = (float*)d_ws;            // 8 MB
    float* kf = qf + TD;                 // 8 MB
    float* vf = kf + TD;                 // 8 MB
    unsigned short* qbuf = (unsigned short*)(vf + TD);   // 4 MB
    unsigned short* kbuf = qbuf + TD;                    // 4 MB
    unsigned short* vbuf = kbuf + TD;                    // 4 MB
    float* y = qf;   // alias: qf no longer needed once attn runs

    dim3 gg(D_MODEL / 64, T_SEQ / 64);
    gemm_nt<<<gg, 256, 0, stream>>>(x, Wq, qf, T_SEQ, D_MODEL, D_MODEL);
    gemm_nt<<<gg, 256, 0, stream>>>(x, Wk, kf, T_SEQ, D_MODEL, D_MODEL);
    gemm_nt<<<gg, 256, 0, stream>>>(x, Wv, vf, T_SEQ, D_MODEL, D_MODEL);

    norm_rope<<<dim3(T_SEQ, NH), 64, 0, stream>>>(qf, kf, vf, vi, lamb, qbuf, kbuf, vbuf);

    attn_mfma<<<dim3(T_SEQ / 64, NH), 256, 0, stream>>>(qbuf, kbuf, vbuf, sink, y);

    gemm_nt<<<gg, 256, 0, stream>>>(y, Wo, out, T_SEQ, D_MODEL, D_MODEL);
}

// Round 4
// 208.984 us; speedup vs baseline: 10.9083x; 2.7106x over previous
//
#include <hip/hip_runtime.h>
#include <math.h>

#define T_SEQ 2048
#define D_MODEL 1024
#define NH 16
#define HD 64
#define RMS_EPS 1.1920928955078125e-07f

typedef unsigned short ushort_t;
typedef __attribute__((ext_vector_type(8))) short short8;
typedef __attribute__((ext_vector_type(8))) unsigned short ushort8;
typedef __attribute__((ext_vector_type(4))) float f32x4;

static __device__ __forceinline__ unsigned short f2bf(float f) {
    union { float f; unsigned u; } v; v.f = f;
    unsigned r = v.u + 0x7fff + ((v.u >> 16) & 1);   // RNE
    return (unsigned short)(r >> 16);
}
static __device__ __forceinline__ float bf2f(unsigned short b) {
    union { unsigned u; float f; } v; v.u = ((unsigned)b) << 16;
    return v.f;
}
static __device__ __forceinline__ void gl_lds16(const ushort_t* g, ushort_t* l) {
    __builtin_amdgcn_global_load_lds(
        (const __attribute__((address_space(1))) unsigned int*)g,
        (__attribute__((address_space(3))) unsigned int*)l, 16, 0, 0);
}

// ---------------------------------------------------------------------------
// Cast f32 -> bf16: x (2M elements, segs 0-1) and the 4 weights (1M each).
// ---------------------------------------------------------------------------
__global__ __launch_bounds__(256) void cast_to_bf16(
    const float* __restrict__ x, const float* __restrict__ wq,
    const float* __restrict__ wk, const float* __restrict__ wv,
    const float* __restrict__ wo,
    ushort_t* __restrict__ xb, ushort_t* __restrict__ wqb,
    ushort_t* __restrict__ wkb, ushort_t* __restrict__ wvb,
    ushort_t* __restrict__ wob) {
    const int seg = blockIdx.y;
    const float* src; ushort_t* dst; size_t base = 0;
    if (seg == 0)      { src = x;  dst = xb; }
    else if (seg == 1) { src = x;  dst = xb; base = 1u << 20; }
    else if (seg == 2) { src = wq; dst = wqb; }
    else if (seg == 3) { src = wk; dst = wkb; }
    else if (seg == 4) { src = wv; dst = wvb; }
    else               { src = wo; dst = wob; }
    const size_t i = base + ((size_t)blockIdx.x * 256 + threadIdx.x) * 8;
    float4 a = *(const float4*)&src[i];
    float4 b = *(const float4*)&src[i + 4];
    ushort8 o;
    o[0] = f2bf(a.x); o[1] = f2bf(a.y); o[2] = f2bf(a.z); o[3] = f2bf(a.w);
    o[4] = f2bf(b.x); o[5] = f2bf(b.y); o[6] = f2bf(b.z); o[7] = f2bf(b.w);
    *(ushort8*)&dst[i] = o;
}

// ---------------------------------------------------------------------------
// bf16 MFMA GEMM: C[M,N] = A[M,K] @ B[N,K]^T. m97-style 2-phase structure:
// 128x128 tile, BK=64, 4 waves 2x2 (each 64x64 = 4x4 frags of 16x16x32),
// global_load_lds(16B) staging into linear LDS, ds_read_b128 frag loads.
// blockIdx.z selects (B,C) pair for the batched QKV case.
// Frag layouts (HW-verified r2): A/B [row|col=l&15][k=8*(l>>4)+j],
// C/D [row=(l>>4)*4+r][col=l&15].
// ---------------------------------------------------------------------------
template<bool BF16OUT>
__global__ __launch_bounds__(256) void gemm_bf16_nt(
    const ushort_t* __restrict__ A,
    const ushort_t* __restrict__ B0, const ushort_t* __restrict__ B1,
    const ushort_t* __restrict__ B2,
    void* __restrict__ C0, void* __restrict__ C1, void* __restrict__ C2,
    int M, int N, int K) {
    __shared__ ushort_t As[128 * 64];   // 16 KB, row-major [128][64]
    __shared__ ushort_t Bs[128 * 64];   // 16 KB

    const int z = blockIdx.z;
    const ushort_t* B = (z == 0) ? B0 : (z == 1) ? B1 : B2;
    void* Cv          = (z == 0) ? C0 : (z == 1) ? C1 : C2;

    const int tid = threadIdx.x;
    const int w = tid >> 6;
    const int l = tid & 63;
    const int wr = w >> 1, wc = w & 1;
    const int l16 = l & 15, g4 = l >> 4;
    const int row0 = blockIdx.y * 128;
    const int col0 = blockIdx.x * 128;

    // staging: thread t covers row = i*32 + t/8, cols 8*(t&7)..+7 (16B)
    const int srow = tid >> 3;
    const int scol = (tid & 7) * 8;
    const ushort_t* ga = A + (size_t)(row0 + srow) * K + scol;
    const ushort_t* gb = B + (size_t)(col0 + srow) * K + scol;
    ushort_t* lA = &As[w * 512];   // wave-uniform LDS base (byte w*1024)
    ushort_t* lB = &Bs[w * 512];

    f32x4 acc[4][4];
#pragma unroll
    for (int m = 0; m < 4; ++m)
#pragma unroll
        for (int n = 0; n < 4; ++n)
            acc[m][n] = (f32x4){0.0f, 0.0f, 0.0f, 0.0f};

    for (int k0 = 0; k0 < K; k0 += 64) {
        __syncthreads();   // all waves done reading LDS for prev tile
#pragma unroll
        for (int i = 0; i < 4; ++i) {
            gl_lds16(ga + (size_t)i * 32 * K + k0, lA + i * 2048);
            gl_lds16(gb + (size_t)i * 32 * K + k0, lB + i * 2048);
        }
        __syncthreads();   // drains vmcnt, data visible
#pragma unroll
        for (int kk = 0; kk < 2; ++kk) {
            short8 af[4], bfr[4];
#pragma unroll
            for (int m = 0; m < 4; ++m)
                af[m] = *(const short8*)&As[(wr * 64 + m * 16 + l16) * 64 + kk * 32 + g4 * 8];
#pragma unroll
            for (int n = 0; n < 4; ++n)
                bfr[n] = *(const short8*)&Bs[(wc * 64 + n * 16 + l16) * 64 + kk * 32 + g4 * 8];
#pragma unroll
            for (int m = 0; m < 4; ++m)
#pragma unroll
                for (int n = 0; n < 4; ++n)
                    acc[m][n] = __builtin_amdgcn_mfma_f32_16x16x32_bf16(af[m], bfr[n], acc[m][n], 0, 0, 0);
        }
    }

#pragma unroll
    for (int m = 0; m < 4; ++m) {
        const int grow = row0 + wr * 64 + m * 16 + g4 * 4;
#pragma unroll
        for (int n = 0; n < 4; ++n) {
            const int gcol = col0 + wc * 64 + n * 16 + l16;
#pragma unroll
            for (int r = 0; r < 4; ++r) {
                if (BF16OUT)
                    ((ushort_t*)Cv)[(size_t)(grow + r) * N + gcol] = f2bf(acc[m][n][r]);
                else
                    ((float*)Cv)[(size_t)(grow + r) * N + gcol] = acc[m][n][r];
            }
        }
    }
}

// ---------------------------------------------------------------------------
// In-place on bf16 q,k,v: v = (1-lam)*v + lam*vi ; q,k = rmsnorm ; rope.
// 4 waves/block, wave w handles (t, h = by*4+w). exp2f replaces powf.
// ---------------------------------------------------------------------------
__global__ __launch_bounds__(256) void norm_rope(ushort_t* __restrict__ qb,
                                                 ushort_t* __restrict__ kb,
                                                 ushort_t* __restrict__ vb,
                                                 const float* __restrict__ vi,
                                                 const float* __restrict__ lamb) {
    const int w = threadIdx.x >> 6;
    const int lane = threadIdx.x & 63;
    const int t = blockIdx.x;
    const int h = blockIdx.y * 4 + w;
    const size_t idx = (size_t)t * D_MODEL + h * HD + lane;

    const float lam = lamb[0];
    float qv = bf2f(qb[idx]);
    float kv = bf2f(kb[idx]);
    float vv = (1.0f - lam) * bf2f(vb[idx]) + lam * vi[idx];
    vb[idx] = f2bf(vv);

    float sq = qv * qv;
    float sk = kv * kv;
#pragma unroll
    for (int m = 1; m <= 32; m <<= 1) {
        sq += __shfl_xor(sq, m, 64);
        sk += __shfl_xor(sk, m, 64);
    }
    const float rq = rsqrtf(sq * (1.0f / 64.0f) + RMS_EPS);
    const float rk = rsqrtf(sk * (1.0f / 64.0f) + RMS_EPS);
    float qn = qv * rq;
    float kn = kv * rk;

    // inv_freq = 10000^(-i/32) = 2^(-log2(1e4)/32 * i)
    const int i = lane & 31;
    const float inv = exp2f(-0.4152410118609203f * (float)i);
    const float ang = (float)t * inv;
    float c, s;
    sincosf(ang, &s, &c);
    float qp = __shfl_xor(qn, 32, 64);
    float kp = __shfl_xor(kn, 32, 64);
    float qo, ko;
    if (lane < 32) {
        qo = qn * c + qp * s;
        ko = kn * c + kp * s;
    } else {
        qo = qn * c - qp * s;
        ko = kn * c - kp * s;
    }
    qb[idx] = f2bf(qo);
    kb[idx] = f2bf(ko);
}

// ---------------------------------------------------------------------------
// Flash attention, bf16 MFMA (16x16x32), unchanged structure from r3;
// now writes bf16 y for the Wo MFMA GEMM.
// ---------------------------------------------------------------------------
__global__ __launch_bounds__(256) void attn_mfma(const ushort_t* __restrict__ qb,
                                                 const ushort_t* __restrict__ kb,
                                                 const ushort_t* __restrict__ vb,
                                                 const float* __restrict__ sink,
                                                 ushort_t* __restrict__ yb) {
    const int qt = blockIdx.x;
    const int h  = blockIdx.y;

    __shared__ ushort_t Vt[64][72];
    __shared__ ushort_t Pl[4][16][72];

    const int tid  = threadIdx.x;
    const int w    = tid >> 6;
    const int lane = tid & 63;
    const int l16  = lane & 15;
    const int g4   = lane >> 4;

    const size_t qoff = (size_t)(qt * 64 + w * 16 + l16) * D_MODEL + h * HD;
    short8 aq0 = *(const short8*)&qb[qoff + 8 * g4];
    short8 aq1 = *(const short8*)&qb[qoff + 32 + 8 * g4];

    float m[4], lsum[4];
    f32x4 acc[4];
#pragma unroll
    for (int r = 0; r < 4; ++r) {
        m[r] = -INFINITY; lsum[r] = 0.0f;
        acc[r] = (f32x4){0.0f, 0.0f, 0.0f, 0.0f};
    }

    for (int kt = 0; kt <= qt; ++kt) {
        {
            const size_t voff = (size_t)(kt * 64 + lane) * D_MODEL + h * HD + w * 16;
            ushort8 v0 = *(const ushort8*)&vb[voff];
            ushort8 v1 = *(const ushort8*)&vb[voff + 8];
#pragma unroll
            for (int j = 0; j < 8; ++j) {
                Vt[w * 16 + j][lane]     = v0[j];
                Vt[w * 16 + 8 + j][lane] = v1[j];
            }
        }
        __syncthreads();

        float p[4][4];
        float mt[4] = {-INFINITY, -INFINITY, -INFINITY, -INFINITY};
#pragma unroll
        for (int s = 0; s < 4; ++s) {
            const size_t koff = (size_t)(kt * 64 + s * 16 + l16) * D_MODEL + h * HD;
            short8 bk0 = *(const short8*)&kb[koff + 8 * g4];
            short8 bk1 = *(const short8*)&kb[koff + 32 + 8 * g4];
            f32x4 sf = (f32x4){0.0f, 0.0f, 0.0f, 0.0f};
            sf = __builtin_amdgcn_mfma_f32_16x16x32_bf16(aq0, bk0, sf, 0, 0, 0);
            sf = __builtin_amdgcn_mfma_f32_16x16x32_bf16(aq1, bk1, sf, 0, 0, 0);
            const int kglob = kt * 64 + s * 16 + l16;
#pragma unroll
            for (int r = 0; r < 4; ++r) {
                float sc = sf[r] * 0.125f;
                const int qglob = qt * 64 + w * 16 + g4 * 4 + r;
                if (kglob > qglob) sc = -INFINITY;
                p[s][r] = sc;
                mt[r] = fmaxf(mt[r], sc);
            }
        }
#pragma unroll
        for (int mk = 1; mk <= 8; mk <<= 1)
#pragma unroll
            for (int r = 0; r < 4; ++r)
                mt[r] = fmaxf(mt[r], __shfl_xor(mt[r], mk, 64));

        float corr[4], ps[4];
#pragma unroll
        for (int r = 0; r < 4; ++r) {
            const float mnew = fmaxf(m[r], mt[r]);
            corr[r] = expf(m[r] - mnew);
            m[r] = mnew;
            ps[r] = 0.0f;
        }
#pragma unroll
        for (int s = 0; s < 4; ++s)
#pragma unroll
            for (int r = 0; r < 4; ++r) {
                const float pv = expf(p[s][r] - m[r]);
                ps[r] += pv;
                Pl[w][g4 * 4 + r][s * 16 + l16] = f2bf(pv);
            }
#pragma unroll
        for (int mk = 1; mk <= 8; mk <<= 1)
#pragma unroll
            for (int r = 0; r < 4; ++r)
                ps[r] += __shfl_xor(ps[r], mk, 64);
#pragma unroll
        for (int r = 0; r < 4; ++r) {
            lsum[r] = lsum[r] * corr[r] + ps[r];
#pragma unroll
            for (int d = 0; d < 4; ++d) acc[d][r] *= corr[r];
        }

        short8 pa0 = *(const short8*)&Pl[w][l16][8 * g4];
        short8 pa1 = *(const short8*)&Pl[w][l16][32 + 8 * g4];
#pragma unroll
        for (int d = 0; d < 4; ++d) {
            short8 bv0 = *(const short8*)&Vt[d * 16 + l16][8 * g4];
            short8 bv1 = *(const short8*)&Vt[d * 16 + l16][32 + 8 * g4];
            acc[d] = __builtin_amdgcn_mfma_f32_16x16x32_bf16(pa0, bv0, acc[d], 0, 0, 0);
            acc[d] = __builtin_amdgcn_mfma_f32_16x16x32_bf16(pa1, bv1, acc[d], 0, 0, 0);
        }
        __syncthreads();
    }

    const float sw = sink[h];
#pragma unroll
    for (int r = 0; r < 4; ++r) {
        const float lse = m[r] + logf(lsum[r]);
        const float scale = 1.0f / (1.0f + expf(-(lse - sw)));
        const float f = scale / lsum[r];
        const size_t yoff = (size_t)(qt * 64 + w * 16 + g4 * 4 + r) * D_MODEL + h * HD + l16;
#pragma unroll
        for (int d = 0; d < 4; ++d)
            yb[yoff + d * 16] = f2bf(acc[d][r] * f);
    }
}

// ---------------------------------------------------------------------------
extern "C" void kernel_launch(void* const* d_in, const int* in_sizes, int n_in,
                              void* d_out, int out_size, void* d_ws, size_t ws_size,
                              hipStream_t stream) {
    const float* x    = (const float*)d_in[0];
    const float* vi   = (const float*)d_in[1];
    const float* Wq   = (const float*)d_in[2];
    const float* Wk   = (const float*)d_in[3];
    const float* Wv   = (const float*)d_in[4];
    const float* Wo   = (const float*)d_in[5];
    const float* lamb = (const float*)d_in[6];
    const float* sink = (const float*)d_in[7];
    float* out = (float*)d_out;

    const size_t TD = (size_t)T_SEQ * D_MODEL;   // 2M elements
    ushort_t* qbuf = (ushort_t*)d_ws;            // 4 MB
    ushort_t* kbuf = qbuf + TD;                  // 4 MB
    ushort_t* vbuf = kbuf + TD;                  // 4 MB
    ushort_t* xb   = vbuf + TD;                  // 4 MB
    ushort_t* yb   = xb + TD;                    // 4 MB
    ushort_t* wqb  = yb + TD;                    // 2 MB
    ushort_t* wkb  = wqb + (1u << 20);           // 2 MB
    ushort_t* wvb  = wkb + (1u << 20);           // 2 MB
    ushort_t* wob  = wvb + (1u << 20);           // 2 MB  (28 MB total)

    cast_to_bf16<<<dim3(512, 6), 256, 0, stream>>>(x, Wq, Wk, Wv, Wo,
                                                   xb, wqb, wkb, wvb, wob);

    gemm_bf16_nt<true><<<dim3(D_MODEL / 128, T_SEQ / 128, 3), 256, 0, stream>>>(
        xb, wqb, wkb, wvb, qbuf, kbuf, vbuf, T_SEQ, D_MODEL, D_MODEL);

    norm_rope<<<dim3(T_SEQ, NH / 4), 256, 0, stream>>>(qbuf, kbuf, vbuf, vi, lamb);

    attn_mfma<<<dim3(T_SEQ / 64, NH), 256, 0, stream>>>(qbuf, kbuf, vbuf, sink, yb);

    gemm_bf16_nt<false><<<dim3(D_MODEL / 128, T_SEQ / 128, 1), 256, 0, stream>>>(
        yb, wob, wob, wob, out, out, out, T_SEQ, D_MODEL, D_MODEL);
}

// Round 5
// 118.031 us; speedup vs baseline: 19.3141x; 1.7706x over previous
//
#include <hip/hip_runtime.h>
#include <math.h>

#define T_SEQ 2048
#define D_MODEL 1024
#define NH 16
#define HD 64
#define RMS_EPS 1.1920928955078125e-07f

typedef unsigned short ushort_t;
typedef __attribute__((ext_vector_type(8))) short short8;
typedef __attribute__((ext_vector_type(8))) unsigned short ushort8;
typedef __attribute__((ext_vector_type(4))) float f32x4;

static __device__ __forceinline__ unsigned short f2bf(float f) {
    union { float f; unsigned u; } v; v.f = f;
    unsigned r = v.u + 0x7fff + ((v.u >> 16) & 1);   // RNE
    return (unsigned short)(r >> 16);
}
static __device__ __forceinline__ float bf2f(unsigned short b) {
    union { unsigned u; float f; } v; v.u = ((unsigned)b) << 16;
    return v.f;
}
static __device__ __forceinline__ void gl_lds16(const ushort_t* g, ushort_t* l) {
    __builtin_amdgcn_global_load_lds(
        (const __attribute__((address_space(1))) unsigned int*)g,
        (__attribute__((address_space(3))) unsigned int*)l, 16, 0, 0);
}

// ---------------------------------------------------------------------------
// Cast f32 -> bf16: x (2M elements, segs 0-1) and the 4 weights (1M each).
// ---------------------------------------------------------------------------
__global__ __launch_bounds__(256) void cast_to_bf16(
    const float* __restrict__ x, const float* __restrict__ wq,
    const float* __restrict__ wk, const float* __restrict__ wv,
    const float* __restrict__ wo,
    ushort_t* __restrict__ xb, ushort_t* __restrict__ wqb,
    ushort_t* __restrict__ wkb, ushort_t* __restrict__ wvb,
    ushort_t* __restrict__ wob) {
    const int seg = blockIdx.y;
    const float* src; ushort_t* dst; size_t base = 0;
    if (seg == 0)      { src = x;  dst = xb; }
    else if (seg == 1) { src = x;  dst = xb; base = 1u << 20; }
    else if (seg == 2) { src = wq; dst = wqb; }
    else if (seg == 3) { src = wk; dst = wkb; }
    else if (seg == 4) { src = wv; dst = wvb; }
    else               { src = wo; dst = wob; }
    const size_t i = base + ((size_t)blockIdx.x * 256 + threadIdx.x) * 8;
    float4 a = *(const float4*)&src[i];
    float4 b = *(const float4*)&src[i + 4];
    ushort8 o;
    o[0] = f2bf(a.x); o[1] = f2bf(a.y); o[2] = f2bf(a.z); o[3] = f2bf(a.w);
    o[4] = f2bf(b.x); o[5] = f2bf(b.y); o[6] = f2bf(b.z); o[7] = f2bf(b.w);
    *(ushort8*)&dst[i] = o;
}

// ---------------------------------------------------------------------------
// bf16 MFMA GEMM (unchanged from r4): C[M,N] = A[M,K] @ B[N,K]^T.
// 128x128 tile, BK=64, 4 waves 2x2, global_load_lds(16B), ds_read_b128.
// ---------------------------------------------------------------------------
template<bool BF16OUT>
__global__ __launch_bounds__(256) void gemm_bf16_nt(
    const ushort_t* __restrict__ A,
    const ushort_t* __restrict__ B0, const ushort_t* __restrict__ B1,
    const ushort_t* __restrict__ B2,
    void* __restrict__ C0, void* __restrict__ C1, void* __restrict__ C2,
    int M, int N, int K) {
    __shared__ ushort_t As[128 * 64];
    __shared__ ushort_t Bs[128 * 64];

    const int z = blockIdx.z;
    const ushort_t* B = (z == 0) ? B0 : (z == 1) ? B1 : B2;
    void* Cv          = (z == 0) ? C0 : (z == 1) ? C1 : C2;

    const int tid = threadIdx.x;
    const int w = tid >> 6;
    const int l = tid & 63;
    const int wr = w >> 1, wc = w & 1;
    const int l16 = l & 15, g4 = l >> 4;
    const int row0 = blockIdx.y * 128;
    const int col0 = blockIdx.x * 128;

    const int srow = tid >> 3;
    const int scol = (tid & 7) * 8;
    const ushort_t* ga = A + (size_t)(row0 + srow) * K + scol;
    const ushort_t* gb = B + (size_t)(col0 + srow) * K + scol;
    ushort_t* lA = &As[w * 512];
    ushort_t* lB = &Bs[w * 512];

    f32x4 acc[4][4];
#pragma unroll
    for (int m = 0; m < 4; ++m)
#pragma unroll
        for (int n = 0; n < 4; ++n)
            acc[m][n] = (f32x4){0.0f, 0.0f, 0.0f, 0.0f};

    for (int k0 = 0; k0 < K; k0 += 64) {
        __syncthreads();
#pragma unroll
        for (int i = 0; i < 4; ++i) {
            gl_lds16(ga + (size_t)i * 32 * K + k0, lA + i * 2048);
            gl_lds16(gb + (size_t)i * 32 * K + k0, lB + i * 2048);
        }
        __syncthreads();
#pragma unroll
        for (int kk = 0; kk < 2; ++kk) {
            short8 af[4], bfr[4];
#pragma unroll
            for (int m = 0; m < 4; ++m)
                af[m] = *(const short8*)&As[(wr * 64 + m * 16 + l16) * 64 + kk * 32 + g4 * 8];
#pragma unroll
            for (int n = 0; n < 4; ++n)
                bfr[n] = *(const short8*)&Bs[(wc * 64 + n * 16 + l16) * 64 + kk * 32 + g4 * 8];
#pragma unroll
            for (int m = 0; m < 4; ++m)
#pragma unroll
                for (int n = 0; n < 4; ++n)
                    acc[m][n] = __builtin_amdgcn_mfma_f32_16x16x32_bf16(af[m], bfr[n], acc[m][n], 0, 0, 0);
        }
    }

#pragma unroll
    for (int m = 0; m < 4; ++m) {
        const int grow = row0 + wr * 64 + m * 16 + g4 * 4;
#pragma unroll
        for (int n = 0; n < 4; ++n) {
            const int gcol = col0 + wc * 64 + n * 16 + l16;
#pragma unroll
            for (int r = 0; r < 4; ++r) {
                if (BF16OUT)
                    ((ushort_t*)Cv)[(size_t)(grow + r) * N + gcol] = f2bf(acc[m][n][r]);
                else
                    ((float*)Cv)[(size_t)(grow + r) * N + gcol] = acc[m][n][r];
            }
        }
    }
}

// ---------------------------------------------------------------------------
// In-place on bf16 q,k,v: v-blend, rmsnorm, rope (unchanged from r4).
// ---------------------------------------------------------------------------
__global__ __launch_bounds__(256) void norm_rope(ushort_t* __restrict__ qb,
                                                 ushort_t* __restrict__ kb,
                                                 ushort_t* __restrict__ vb,
                                                 const float* __restrict__ vi,
                                                 const float* __restrict__ lamb) {
    const int w = threadIdx.x >> 6;
    const int lane = threadIdx.x & 63;
    const int t = blockIdx.x;
    const int h = blockIdx.y * 4 + w;
    const size_t idx = (size_t)t * D_MODEL + h * HD + lane;

    const float lam = lamb[0];
    float qv = bf2f(qb[idx]);
    float kv = bf2f(kb[idx]);
    float vv = (1.0f - lam) * bf2f(vb[idx]) + lam * vi[idx];
    vb[idx] = f2bf(vv);

    float sq = qv * qv;
    float sk = kv * kv;
#pragma unroll
    for (int m = 1; m <= 32; m <<= 1) {
        sq += __shfl_xor(sq, m, 64);
        sk += __shfl_xor(sk, m, 64);
    }
    const float rq = rsqrtf(sq * (1.0f / 64.0f) + RMS_EPS);
    const float rk = rsqrtf(sk * (1.0f / 64.0f) + RMS_EPS);
    float qn = qv * rq;
    float kn = kv * rk;

    const int i = lane & 31;
    const float inv = exp2f(-0.4152410118609203f * (float)i);
    const float ang = (float)t * inv;
    float c, s;
    sincosf(ang, &s, &c);
    float qp = __shfl_xor(qn, 32, 64);
    float kp = __shfl_xor(kn, 32, 64);
    float qo, ko;
    if (lane < 32) {
        qo = qn * c + qp * s;
        ko = kn * c + kp * s;
    } else {
        qo = qn * c - qp * s;
        ko = kn * c - kp * s;
    }
    qb[idx] = f2bf(qo);
    kb[idx] = f2bf(ko);
}

// ---------------------------------------------------------------------------
// Flash attention v2: swapped QK^T (mfma(K,Q) -> lane owns one q-row),
// register-prefetch of next K/V tile, double-buffered V in LDS (1 barrier/
// iter), balanced grid pairing {p, 31-p}, __expf softmax, diagonal-only mask.
//
// Layouts (HW-verified): A/B frag [row|col=l&15][k=8*(l>>4)+j],
// C/D [row=(l>>4)*4+r][col=l&15].
// Swapped S^T: sf[s][r] = S[key=s*16+g4*4+r][q=l16] -> per-lane q = l16.
// PV: A=P[q=l16][key], B=V^T[key][d]; D[q=g4*4+r][d=l16].
// ---------------------------------------------------------------------------
__global__ __launch_bounds__(256) void attn_mfma(const ushort_t* __restrict__ qb,
                                                 const ushort_t* __restrict__ kb,
                                                 const ushort_t* __restrict__ vb,
                                                 const float* __restrict__ sink,
                                                 ushort_t* __restrict__ yb) {
    // balanced decode: blocks b and b+256 share h and get qt = {p, 31-p}
    const int b    = blockIdx.x;
    const int half = b >> 8;
    const int idx  = b & 255;
    const int h    = idx >> 4;
    const int p    = idx & 15;
    const int qt   = half ? (31 - p) : p;

    __shared__ ushort_t Vt[2][64][72];      // V transposed, double-buffered
    __shared__ ushort_t Pl[4][16][72];      // per-wave P (wave-local)

    const int tid  = threadIdx.x;
    const int w    = tid >> 6;
    const int lane = tid & 63;
    const int l16  = lane & 15;
    const int g4   = lane >> 4;

    // Q B-frags (persist): B[k=d][col=q=l16]
    const size_t qoff = (size_t)(qt * 64 + w * 16 + l16) * D_MODEL + h * HD;
    const short8 q0 = *(const short8*)&qb[qoff + 8 * g4];
    const short8 q1 = *(const short8*)&qb[qoff + 32 + 8 * g4];

    // current K A-frags + V staging regs (tile 0)
    short8 ka0[4], ka1[4];
    ushort8 va0, va1;
#pragma unroll
    for (int s = 0; s < 4; ++s) {
        const size_t koff = (size_t)(s * 16 + l16) * D_MODEL + h * HD;
        ka0[s] = *(const short8*)&kb[koff + 8 * g4];
        ka1[s] = *(const short8*)&kb[koff + 32 + 8 * g4];
    }
    {
        const size_t voff = (size_t)lane * D_MODEL + h * HD + w * 16;
        va0 = *(const ushort8*)&vb[voff];
        va1 = *(const ushort8*)&vb[voff + 8];
    }

    float m = -INFINITY, lsum = 0.0f;
    f32x4 acc[4];
#pragma unroll
    for (int d = 0; d < 4; ++d) acc[d] = (f32x4){0.0f, 0.0f, 0.0f, 0.0f};

    for (int kt = 0; kt <= qt; ++kt) {
        const int cur = kt & 1;

        // stage current V regs -> Vt[cur] (transposed: [d][key])
#pragma unroll
        for (int j = 0; j < 8; ++j) {
            Vt[cur][w * 16 + j][lane]     = va0[j];
            Vt[cur][w * 16 + 8 + j][lane] = va1[j];
        }

        // prefetch next tile K/V into regs (overlaps compute below)
        short8 kn0[4], kn1[4];
        ushort8 vn0, vn1;
        if (kt < qt) {
#pragma unroll
            for (int s = 0; s < 4; ++s) {
                const size_t koff = (size_t)((kt + 1) * 64 + s * 16 + l16) * D_MODEL + h * HD;
                kn0[s] = *(const short8*)&kb[koff + 8 * g4];
                kn1[s] = *(const short8*)&kb[koff + 32 + 8 * g4];
            }
            const size_t voff = (size_t)((kt + 1) * 64 + lane) * D_MODEL + h * HD + w * 16;
            vn0 = *(const ushort8*)&vb[voff];
            vn1 = *(const ushort8*)&vb[voff + 8];
        }

        __syncthreads();   // Vt[cur] fully staged (also fences prev-iter reads)

        // ---- S^T = K Q^T : sf[s][r] = S[key=s*16+g4*4+r][q=l16] ----
        f32x4 sf[4];
#pragma unroll
        for (int s = 0; s < 4; ++s) {
            f32x4 t = (f32x4){0.0f, 0.0f, 0.0f, 0.0f};
            t = __builtin_amdgcn_mfma_f32_16x16x32_bf16(ka0[s], q0, t, 0, 0, 0);
            t = __builtin_amdgcn_mfma_f32_16x16x32_bf16(ka1[s], q1, t, 0, 0, 0);
            sf[s] = t;
        }

        float mt = -INFINITY;
        if (kt == qt) {
            // diagonal tile: mask key_local > q_local
            const int ql = w * 16 + l16;
#pragma unroll
            for (int s = 0; s < 4; ++s)
#pragma unroll
                for (int r = 0; r < 4; ++r) {
                    const float sc = sf[s][r] * 0.125f;
                    sf[s][r] = (s * 16 + g4 * 4 + r > ql) ? -INFINITY : sc;
                    mt = fmaxf(mt, sf[s][r]);
                }
        } else {
#pragma unroll
            for (int s = 0; s < 4; ++s)
#pragma unroll
                for (int r = 0; r < 4; ++r) {
                    sf[s][r] *= 0.125f;
                    mt = fmaxf(mt, sf[s][r]);
                }
        }
        // row-max: q-row spread over lanes {l16, l16+16, l16+32, l16+48}
        mt = fmaxf(mt, __shfl_xor(mt, 16, 64));
        mt = fmaxf(mt, __shfl_xor(mt, 32, 64));

        const float mnew = fmaxf(m, mt);
        const float corr = __expf(m - mnew);   // exp(-inf)=0 first tile
        m = mnew;

        float ps = 0.0f;
#pragma unroll
        for (int s = 0; s < 4; ++s) {
            const float e0 = __expf(sf[s][0] - m);
            const float e1 = __expf(sf[s][1] - m);
            const float e2 = __expf(sf[s][2] - m);
            const float e3 = __expf(sf[s][3] - m);
            ps += (e0 + e1) + (e2 + e3);
            // packed b64 write: keys s*16+g4*4 .. +3 of q-row l16
            uint2 pk;
            pk.x = (unsigned)f2bf(e0) | ((unsigned)f2bf(e1) << 16);
            pk.y = (unsigned)f2bf(e2) | ((unsigned)f2bf(e3) << 16);
            *(uint2*)&Pl[w][l16][s * 16 + g4 * 4] = pk;
        }
        ps += __shfl_xor(ps, 16, 64);
        ps += __shfl_xor(ps, 32, 64);
        lsum = lsum * corr + ps;

        // rescale acc: acc rows are q = g4*4+r -> fetch corr from lane g4*4+r
        float corrq[4];
#pragma unroll
        for (int r = 0; r < 4; ++r) corrq[r] = __shfl(corr, g4 * 4 + r, 64);
#pragma unroll
        for (int d = 0; d < 4; ++d)
#pragma unroll
            for (int r = 0; r < 4; ++r) acc[d][r] *= corrq[r];

        // ---- PV: A = P[q=l16][key=f*32+8*g4+j] from wave-local LDS ----
        const short8 pa0 = *(const short8*)&Pl[w][l16][8 * g4];
        const short8 pa1 = *(const short8*)&Pl[w][l16][32 + 8 * g4];
#pragma unroll
        for (int d = 0; d < 4; ++d) {
            const short8 v0 = *(const short8*)&Vt[cur][d * 16 + l16][8 * g4];
            const short8 v1 = *(const short8*)&Vt[cur][d * 16 + l16][32 + 8 * g4];
            acc[d] = __builtin_amdgcn_mfma_f32_16x16x32_bf16(pa0, v0, acc[d], 0, 0, 0);
            acc[d] = __builtin_amdgcn_mfma_f32_16x16x32_bf16(pa1, v1, acc[d], 0, 0, 0);
        }

        // rotate prefetched regs
        if (kt < qt) {
#pragma unroll
            for (int s = 0; s < 4; ++s) { ka0[s] = kn0[s]; ka1[s] = kn1[s]; }
            va0 = vn0; va1 = vn1;
        }
    }

    // epilogue: per-q scale lives in lane l16=q; acc rows are q=g4*4+r
    const float lse = m + __logf(lsum);
    const float scale = 1.0f / (1.0f + __expf(-(lse - sink[h])));
    const float fv = scale / lsum;
    float fq[4];
#pragma unroll
    for (int r = 0; r < 4; ++r) fq[r] = __shfl(fv, g4 * 4 + r, 64);

#pragma unroll
    for (int r = 0; r < 4; ++r) {
        const size_t yoff = (size_t)(qt * 64 + w * 16 + g4 * 4 + r) * D_MODEL + h * HD + l16;
#pragma unroll
        for (int d = 0; d < 4; ++d)
            yb[yoff + d * 16] = f2bf(acc[d][r] * fq[r]);
    }
}

// ---------------------------------------------------------------------------
extern "C" void kernel_launch(void* const* d_in, const int* in_sizes, int n_in,
                              void* d_out, int out_size, void* d_ws, size_t ws_size,
                              hipStream_t stream) {
    const float* x    = (const float*)d_in[0];
    const float* vi   = (const float*)d_in[1];
    const float* Wq   = (const float*)d_in[2];
    const float* Wk   = (const float*)d_in[3];
    const float* Wv   = (const float*)d_in[4];
    const float* Wo   = (const float*)d_in[5];
    const float* lamb = (const float*)d_in[6];
    const float* sink = (const float*)d_in[7];
    float* out = (float*)d_out;

    const size_t TD = (size_t)T_SEQ * D_MODEL;   // 2M elements
    ushort_t* qbuf = (ushort_t*)d_ws;            // 4 MB
    ushort_t* kbuf = qbuf + TD;                  // 4 MB
    ushort_t* vbuf = kbuf + TD;                  // 4 MB
    ushort_t* xb   = vbuf + TD;                  // 4 MB
    ushort_t* yb   = xb + TD;                    // 4 MB
    ushort_t* wqb  = yb + TD;                    // 2 MB
    ushort_t* wkb  = wqb + (1u << 20);           // 2 MB
    ushort_t* wvb  = wkb + (1u << 20);           // 2 MB
    ushort_t* wob  = wvb + (1u << 20);           // 2 MB  (28 MB total)

    cast_to_bf16<<<dim3(512, 6), 256, 0, stream>>>(x, Wq, Wk, Wv, Wo,
                                                   xb, wqb, wkb, wvb, wob);

    gemm_bf16_nt<true><<<dim3(D_MODEL / 128, T_SEQ / 128, 3), 256, 0, stream>>>(
        xb, wqb, wkb, wvb, qbuf, kbuf, vbuf, T_SEQ, D_MODEL, D_MODEL);

    norm_rope<<<dim3(T_SEQ, NH / 4), 256, 0, stream>>>(qbuf, kbuf, vbuf, vi, lamb);

    attn_mfma<<<dim3(T_SEQ / 64 * NH), 256, 0, stream>>>(qbuf, kbuf, vbuf, sink, yb);

    gemm_bf16_nt<false><<<dim3(D_MODEL / 128, T_SEQ / 128, 1), 256, 0, stream>>>(
        yb, wob, wob, wob, out, out, out, T_SEQ, D_MODEL, D_MODEL);
}